// Round 9
// baseline (294.428 us; speedup 1.0000x reference)
//
#include <hip/hip_runtime.h>
#include <math.h>

// Problem: MultiheadSelfAttention_41369124995143 on gfx950
// B=4, T=2048, M=1024, H=8, D=128.
// I/O is fp32 (per reference); internal compute bf16 MFMA with fp32 accum.

typedef unsigned short u16;
typedef __attribute__((ext_vector_type(8))) short short8;   // 8 bf16 = 4 VGPR (MFMA A/B frag)
typedef __attribute__((ext_vector_type(4))) float floatx4;  // MFMA C/D frag

#define MFMA_B16(a, b, c) __builtin_amdgcn_mfma_f32_16x16x32_bf16((a), (b), (c), 0, 0, 0)

__device__ __forceinline__ void async_cp16(const void* g, void* l) {
  // 16B global -> LDS DMA. LDS dest = wave-uniform base + lane*16.
  __builtin_amdgcn_global_load_lds(
      (const __attribute__((address_space(1))) unsigned int*)g,
      (__attribute__((address_space(3))) unsigned int*)l, 16, 0, 0);
}

__device__ __forceinline__ u16 f2bf(float f) {  // RNE float->bf16
  unsigned u = __float_as_uint(f);
  u += 0x7FFFu + ((u >> 16) & 1u);
  return (u16)(u >> 16);
}

__device__ __forceinline__ unsigned cvt_pk_bf16(float lo, float hi) {
  // v_cvt_pk_bf16_f32: dst.lo16 = bf16(lo), dst.hi16 = bf16(hi), RNE.
  unsigned r;
  asm("v_cvt_pk_bf16_f32 %0, %1, %2" : "=v"(r) : "v"(lo), "v"(hi));
  return r;
}

// XOR swizzle: 16B chunk c of logical row stored at physical chunk (c ^ (row&7)).
__device__ __forceinline__ int swz8(int row, int chunk) { return ((chunk ^ (row & 7)) << 3); }

// ---------------------------------------------------------------------------
// prep_all: ALL prep work in ONE kernel.
//   bid [0, 8192):      x fp32 -> bf16           (1024 elems/block)
//   bid [8192, 11264):  wq/wk/wv transpose -> wT (32x32 tiles)
//   bid [11264, 12288): wo transpose -> woT
//   bid [12288, 12800): rope table (256 entries/block); bid 12288 also
//                       zeroes the 256 flash arrival counters (per replay).
// ---------------------------------------------------------------------------
__global__ void prep_all(const float* __restrict__ x, const float* __restrict__ wq,
                         const float* __restrict__ wk, const float* __restrict__ wv,
                         const float* __restrict__ wo, u16* __restrict__ xb,
                         u16* __restrict__ wT, u16* __restrict__ woT,
                         float2* __restrict__ tab, int* __restrict__ cnt) {
  __shared__ float tile[32][33];
  const int bid = blockIdx.x;
  const int tid = threadIdx.x;

  if (bid < 8192) {
    int idx = (bid * 256 + tid) * 4;
    float4 v = *(const float4*)(x + idx);
    ushort4 o = make_ushort4(f2bf(v.x), f2bf(v.y), f2bf(v.z), f2bf(v.w));
    *(ushort4*)(xb + idx) = o;
  } else if (bid < 11264) {
    int id2 = bid - 8192;
    int z = id2 >> 10;            // 0..2 (q,k,v)
    int rem = id2 & 1023;
    int by = rem >> 5, bx = rem & 31;
    const float* src = (z == 0) ? wq : (z == 1) ? wk : wv;
    u16* dst = wT + (size_t)z * 1024 * 1024;
    int h = by >> 2, dt = by & 3;
    int m0 = bx * 32, d0 = dt * 32;
    int tx = tid & 31, ty = tid >> 5;
#pragma unroll
    for (int i = 0; i < 4; i++) {
      int r = ty + i * 8;
      tile[r][tx] = src[((size_t)h * 1024 + m0 + r) * 128 + d0 + tx];
    }
    __syncthreads();
#pragma unroll
    for (int i = 0; i < 4; i++) {
      int r = ty + i * 8;
      dst[((size_t)h * 128 + d0 + r) * 1024 + m0 + tx] = f2bf(tile[tx][r]);
    }
  } else if (bid < 12288) {
    int id2 = bid - 11264;
    int by = id2 >> 5, bx = id2 & 31;
    int r0 = by * 32, c0 = bx * 32;
    int tx = tid & 31, ty = tid >> 5;
#pragma unroll
    for (int i = 0; i < 4; i++) {
      int r = ty + i * 8;
      tile[r][tx] = wo[(size_t)(r0 + r) * 1024 + c0 + tx];
    }
    __syncthreads();
#pragma unroll
    for (int i = 0; i < 4; i++) {
      int r = ty + i * 8;
      woT[(size_t)(c0 + r) * 1024 + r0 + tx] = f2bf(tile[tx][r]);
    }
  } else {
    if (bid == 12288) cnt[tid] = 0;  // zero flash arrival counters (256)
    // rope table: tab[t*64+d] = SQ * {cos,sin}(t * 10000^(-d/64)), fp32.
    // SQ = sqrt((1/128)*log2(e)): Q,K pre-scaled so softmax is plain exp2.
    int idx = (bid - 12288) * 256 + tid;  // 2048*64 entries
    int t = idx >> 6, d = idx & 63;
    const float c1 = -0.20762050593046015f;  // -log2(10000)/64
    const float SQ = 0.10616522f;            // sqrt((1/128)*log2(e))
    float freq = exp2f((float)d * c1);
    float rad = (float)t * freq;
    float s, c;
    sincosf(rad, &s, &c);
    tab[idx] = make_float2(c * SQ, s * SQ);
  }
}

// ---------------------------------------------------------------------------
// GEMM: C[128x128] = A[128xK] * Bt[128xK]^T, K=1024, BK=64, 4 waves,
// wave w owns rows [w*32, w*32+32) x ALL 128 cols (RoPE pairs in-lane).
// MODE 0: QKV projection (by: 0-7 Q, 8-15 K, 16-23 V); A,Bt bf16.
// MODE 1: output projection; fp32 store to out0.
// 128x128 tile kept deliberately: guide m105 measured 128x256 SLOWER (823
// vs 912 TF) at this 2-barrier structure; tile growth pays only with the
// 8-phase schedule.
// ---------------------------------------------------------------------------
template <int MODE>
__launch_bounds__(256, 3)
__global__ void gemm_bt(const u16* __restrict__ A, const u16* __restrict__ Bt,
                        void* __restrict__ out0, u16* __restrict__ out_k,
                        u16* __restrict__ out_v, const float2* __restrict__ ropetab) {
  __shared__ u16 smem[16384];  // As[128*64] | Bs[128*64]; reused as E[128*128] in V epilogue
  u16* As = smem;
  u16* Bs = smem + 8192;
  const int tid = threadIdx.x;
  const int w = tid >> 6, lane = tid & 63, quad = lane >> 4, l15 = lane & 15;
  const int row0 = blockIdx.x * 128;
  const int by = blockIdx.y;
  const int n0 = by * 128;

  floatx4 acc[2][8] = {};

  for (int kt = 0; kt < 16; ++kt) {
    __syncthreads();
#pragma unroll
    for (int i = 0; i < 4; i++) {
      int cidx = (w * 4 + i) * 64 + lane;  // 16B chunk id in 128x64 tile
      int r = cidx >> 3, c = cidx & 7, cg = c ^ (r & 7);
      async_cp16(A + (size_t)(row0 + r) * 1024 + kt * 64 + cg * 8, As + (w * 4 + i) * 512);
      async_cp16(Bt + (size_t)(n0 + r) * 1024 + kt * 64 + cg * 8, Bs + (w * 4 + i) * 512);
    }
    __syncthreads();
#pragma unroll
    for (int ks = 0; ks < 2; ks++) {
      short8 af[2];
#pragma unroll
      for (int mi = 0; mi < 2; mi++) {
        int r = w * 32 + mi * 16 + l15;
        af[mi] = *(const short8*)(As + r * 64 + swz8(r, ks * 4 + quad));
      }
#pragma unroll
      for (int ni = 0; ni < 8; ni++) {
        int n = ni * 16 + l15;
        short8 bf = *(const short8*)(Bs + n * 64 + swz8(n, ks * 4 + quad));
        acc[0][ni] = MFMA_B16(af[0], bf, acc[0][ni]);
        acc[1][ni] = MFMA_B16(af[1], bf, acc[1][ni]);
      }
    }
  }
  __syncthreads();

  if (MODE == 0) {
    int sel = by >> 3, h = by & 7;
    if (sel < 2) {
      // Q or K: in-register RoPE (cols d and d+64 share lane & reg). out [b][h][t][d] bf16.
      u16* dst = sel ? out_k : (u16*)out0;
#pragma unroll
      for (int mi = 0; mi < 2; mi++) {
#pragma unroll
        for (int reg = 0; reg < 4; reg++) {
          int row = row0 + w * 32 + mi * 16 + quad * 4 + reg;  // b*T + t
          int b = row >> 11, t = row & 2047;
          u16* drow = dst + ((size_t)(b * 8 + h) * 2048 + t) * 128;
#pragma unroll
          for (int ni = 0; ni < 4; ni++) {
            int d = ni * 16 + l15;  // 0..63
            float2 cs = ropetab[t * 64 + d];
            float e = acc[mi][ni][reg], o = acc[mi][ni + 4][reg];
            drow[d] = f2bf(e * cs.x - o * cs.y);
            drow[d + 64] = f2bf(e * cs.y + o * cs.x);
          }
        }
      }
    } else {
      // V: LDS transpose, store [b][h][d][t'] bf16 with t' = perm32'd t so
      // flash's PV B-operand k-slots match the in-register P layout:
      //   perm32(j) = ((j>>2)&3)*8 + (j&3) + ((j&16)>>2)
#pragma unroll
      for (int mi = 0; mi < 2; mi++) {
#pragma unroll
        for (int reg = 0; reg < 4; reg++) {
          int r = w * 32 + mi * 16 + quad * 4 + reg;
#pragma unroll
          for (int ni = 0; ni < 8; ni++) {
            int col = ni * 16 + l15;
            smem[r * 128 + swz8(r, col >> 3) + (col & 7)] = f2bf(acc[mi][ni][reg]);
          }
        }
      }
      __syncthreads();
      int tl = tid & 127, dg = tid >> 7;
      int row = row0 + tl;
      int b = row >> 11, t = row & 2047;
      int tp = (t & ~31) | ((((t >> 2) & 3) << 3) | (t & 3) | ((t & 16) >> 2));
      u16* vdst = out_v + (size_t)(b * 8 + h) * 128 * 2048;
#pragma unroll
      for (int dd = 0; dd < 64; dd++) {
        int d = dg * 64 + dd;
        u16 val = smem[tl * 128 + swz8(tl, d >> 3) + (d & 7)];
        vdst[(size_t)d * 2048 + tp] = val;  // consecutive tid -> coalesced
      }
    }
  } else {
    // MODE 1: fp32 store to out [8192][1024]
    float* outf = (float*)out0;
#pragma unroll
    for (int mi = 0; mi < 2; mi++) {
#pragma unroll
      for (int reg = 0; reg < 4; reg++) {
        int row = row0 + w * 32 + mi * 16 + quad * 4 + reg;
#pragma unroll
        for (int ni = 0; ni < 8; ni++) {
          outf[(size_t)row * 1024 + n0 + ni * 16 + l15] = acc[mi][ni][reg];
        }
      }
    }
  }
}

// ---------------------------------------------------------------------------
// Flash attention v9: v8 + in-kernel merge (combine launch eliminated).
//   Balanced j-split (round-7 verified: 17 iters/block, occ 12.3->17.7%,
//   MfmaUtil 13.4->23.5%). Pair (a=p, b=15-p), p=0..7:
//     W0 (id<256):  all of tile a (2p+2) -> direct O; tile-b [0,15-2p)
//     W1 (id>=256): tile-b [15-2p, 32-2p)
//   Tile-b partials are ADDITIVE (fixed-max softmax). NEW: both halves
//   write fp32 partials, then threadfence + atomicAdd(cnt[job],1); the
//   SECOND arriver merges (own regs + other's partial), normalizes, writes
//   O. Bit-identical to the old combine kernel (fp32 add commutes; same
//   normalize); no dispatch-order or co-residency assumption (write-always,
//   no spinning). Removes the combine kernel + one launch boundary.
//   Row-sum via ones-column MFMA. P never touches LDS (swapped QK^T +
//   perm32'd V). Q,K bf16 [bh][t][d]; V bf16 [bh][d][t']; O -> [b][t][h][d].
// ---------------------------------------------------------------------------
__device__ __forceinline__ void stage_kv(const u16* kb, const u16* vb, int jt,
                                         u16* Kd, u16* Vd, int w, int lane) {
#pragma unroll
  for (int i = 0; i < 4; i++) {
    int cidx = (w * 4 + i) * 64 + lane;  // 16B chunk id, 0..1023
    int rK = cidx >> 4, cK = cidx & 15, gK = cK ^ (rK & 7);
    async_cp16(kb + (size_t)(jt * 64 + rK) * 128 + gK * 8, Kd + (w * 4 + i) * 512);
    int rV = cidx >> 3, cV = cidx & 7, gV = cV ^ (rV & 7);
    async_cp16(vb + (size_t)rV * 2048 + jt * 64 + gV * 8, Vd + (w * 4 + i) * 512);
  }
}

__device__ __forceinline__ void attn_tile(
    const u16* __restrict__ qb, const u16* __restrict__ kb, const u16* __restrict__ vb,
    u16* __restrict__ O, float* __restrict__ partp, float* __restrict__ plp,
    const float* __restrict__ partOther, const float* __restrict__ plOther,
    int* __restrict__ cntSlot, int* lastflag,
    int qt, int jb, int je, int w, int lane, int quad, int l15,
    u16* smem, int b, int h, int tid) {
  const int iw = qt * 128 + w * 32;  // wave's first global q-row

  // Q fragments: global reads, no smem dependency -> issue BEFORE the entry
  // barrier so their latency overlaps the barrier wait.
  short8 qf[2][4];
#pragma unroll
  for (int mi = 0; mi < 2; mi++) {
    int qrow = iw + mi * 16 + l15;
#pragma unroll
    for (int ks = 0; ks < 4; ks++)
      qf[mi][ks] = *(const short8*)(qb + (size_t)qrow * 128 + ks * 32 + quad * 8);
  }

  __syncthreads();  // prior phase's readers of smem are done

  short8 onesf;  // bf16 1.0 in all 8 slots: B-operand for row-sum MFMA
#pragma unroll
  for (int i = 0; i < 8; i++) onesf[i] = (short)0x3F80;

  floatx4 accO[2][8] = {};
  floatx4 accLs[2] = {};  // accLs[mi][r] = sum_j P[row(quad,r)][j], all l15 equal

  stage_kv(kb, vb, jb, smem, smem + 16384, w, lane);

  int cur = 0;
  for (int jt = jb; jt < je; ++jt) {
    __syncthreads();  // tile jt ready; other-buffer readers done
    if (jt + 1 < je)
      stage_kv(kb, vb, jt + 1, smem + (cur ^ 1) * 8192, smem + 16384 + (cur ^ 1) * 8192, w, lane);

    const u16* Ks = smem + cur * 8192;
    const u16* Vs = smem + 16384 + cur * 8192;
    const int j0 = jt * 64;

    if (j0 <= iw + 31) {  // else: whole KV tile above this wave's diagonal
      const bool partial = (j0 + 63 > iw);

      // S^T = K Q^T: sa[jj][mi], lane -> (i = l15 of strip mi, j = jj*16+quad*4+r)
      floatx4 sa[4][2] = {};
      __builtin_amdgcn_s_setprio(1);
#pragma unroll
      for (int jj = 0; jj < 4; jj++) {
        const bool ok1 = (j0 + jj * 16 <= iw + 31);
        if (!ok1) continue;
        const bool ok0 = (j0 + jj * 16 <= iw + 15);
#pragma unroll
        for (int ks = 0; ks < 4; ks++) {
          int j = jj * 16 + l15;
          short8 kf = *(const short8*)(Ks + j * 128 + swz8(j, ks * 4 + quad));
          if (ok0) sa[jj][0] = MFMA_B16(kf, qf[0][ks], sa[jj][0]);
          sa[jj][1] = MFMA_B16(kf, qf[1][ks], sa[jj][1]);
        }
      }
      __builtin_amdgcn_s_setprio(0);

      // p = exp2(s) with causal mask; pack to bf16 IN REGISTERS.
      unsigned pk_[2][2][4];
#pragma unroll
      for (int mi = 0; mi < 2; mi++) {
        const int ig = iw + mi * 16 + l15;
#pragma unroll
        for (int jj = 0; jj < 4; jj++) {
          float pv[4];
#pragma unroll
          for (int r = 0; r < 4; r++) {
            float s = sa[jj][mi][r];
            if (partial) {
              int jg = j0 + jj * 16 + quad * 4 + r;
              if (jg > ig) s = -1e30f;  // exp2 -> 0
            }
            pv[r] = exp2f(s);
          }
          pk_[mi][jj >> 1][(jj & 1) * 2 + 0] = cvt_pk_bf16(pv[0], pv[1]);
          pk_[mi][jj >> 1][(jj & 1) * 2 + 1] = cvt_pk_bf16(pv[2], pv[3]);
        }
      }

      // O += P*V; rowsum += P*ones (matrix pipe). V columns pre-permuted so
      // B k-slots match P's in-register layout.
      __builtin_amdgcn_s_setprio(1);
#pragma unroll
      for (int k2 = 0; k2 < 2; k2++) {
        if (k2 == 1 && j0 + 32 > iw + 31) continue;  // upper half fully masked
        union {
          unsigned u[4];
          short8 s8;
        } pa[2];
#pragma unroll
        for (int mi = 0; mi < 2; mi++) {
#pragma unroll
          for (int dw = 0; dw < 4; dw++) pa[mi].u[dw] = pk_[mi][k2][dw];
        }
        accLs[0] = MFMA_B16(pa[0].s8, onesf, accLs[0]);
        accLs[1] = MFMA_B16(pa[1].s8, onesf, accLs[1]);
#pragma unroll
        for (int nt = 0; nt < 8; nt++) {
          int dr = nt * 16 + l15;
          short8 vf = *(const short8*)(Vs + dr * 64 + swz8(dr, k2 * 4 + quad));
          accO[0][nt] = MFMA_B16(pa[0].s8, vf, accO[0][nt]);
          accO[1][nt] = MFMA_B16(pa[1].s8, vf, accO[1][nt]);
        }
      }
      __builtin_amdgcn_s_setprio(0);
    }
    cur ^= 1;
  }

  if (partp == nullptr) {
    // Tile complete: normalize + store O as [b][t][h][d] bf16.
#pragma unroll
    for (int mi = 0; mi < 2; mi++) {
#pragma unroll
      for (int r = 0; r < 4; r++) {
        float inv = 1.0f / fmaxf(accLs[mi][r], 1e-30f);
        int t = iw + mi * 16 + quad * 4 + r;
#pragma unroll
        for (int nt = 0; nt < 8; nt++) {
          O[(((size_t)b * 2048 + t) * 8 + h) * 128 + nt * 16 + l15] =
              f2bf(accO[mi][nt][r] * inv);
        }
      }
    }
  } else {
    // Partial: fp32 numerators [128][128] + row-sums [128].
#pragma unroll
    for (int mi = 0; mi < 2; mi++) {
#pragma unroll
      for (int r = 0; r < 4; r++) {
        int lrow = w * 32 + mi * 16 + quad * 4 + r;
#pragma unroll
        for (int nt = 0; nt < 8; nt++) {
          partp[lrow * 128 + nt * 16 + l15] = accO[mi][nt][r];
        }
        if (l15 == 0) plp[lrow] = accLs[mi][r];
      }
    }
    // Arrival protocol: release own stores, count arrivals; second arriver
    // merges (own regs + other's partial) and writes O. Write-always, no
    // spin -> no co-residency assumption.
    __syncthreads();
    if (tid == 0) {
      __threadfence();
      *lastflag = atomicAdd(cntSlot, 1);
    }
    __syncthreads();
    if (*lastflag == 1) {
      __threadfence();  // acquire other's partial stores
#pragma unroll
      for (int mi = 0; mi < 2; mi++) {
#pragma unroll
        for (int r = 0; r < 4; r++) {
          int lrow = w * 32 + mi * 16 + quad * 4 + r;
          float inv = 1.0f / fmaxf(accLs[mi][r] + plOther[lrow], 1e-30f);
          int t = qt * 128 + lrow;
#pragma unroll
          for (int nt = 0; nt < 8; nt++) {
            float v = accO[mi][nt][r] + partOther[lrow * 128 + nt * 16 + l15];
            O[(((size_t)b * 2048 + t) * 8 + h) * 128 + nt * 16 + l15] = f2bf(v * inv);
          }
        }
      }
    }
  }
}

__launch_bounds__(256, 2)
__global__ void flash_attn(const u16* __restrict__ Q, const u16* __restrict__ Kw,
                           const u16* __restrict__ Vw, u16* __restrict__ O,
                           float* __restrict__ part0, float* __restrict__ part1,
                           float* __restrict__ pls, int* __restrict__ cnt) {
  // 64KB dbuf: K0 [0,8192), K1 [8192,16384), V0 [16384,24576), V1 [24576,32768)
  __shared__ u16 smem[32768];
  __shared__ int lastflag;

  const int tid = threadIdx.x;
  const int w = tid >> 6, lane = tid & 63, quad = lane >> 4, l15 = lane & 15;

  const int id = (int)blockIdx.x;  // 0..511
  const int half = id >> 8;        // 0 = W0, 1 = W1
  const int sub = id & 255;        // job id: p*32 + bh
  const int bh = sub & 31, p = sub >> 5;

  const u16* qb = Q + (size_t)bh * 2048 * 128;
  const u16* kb = Kw + (size_t)bh * 2048 * 128;
  const u16* vb = Vw + (size_t)bh * 128 * 2048;
  const int b = bh >> 3, h = bh & 7;
  const int bt = 15 - p;  // partner tile

  if (half == 0) {
    // tile a complete (2p+2 iters) -> direct O; then tile-b prefix (15-2p).
    attn_tile(qb, kb, vb, O, nullptr, nullptr, nullptr, nullptr, nullptr, &lastflag,
              p, 0, 2 * p + 2, w, lane, quad, l15, smem, b, h, tid);
    attn_tile(qb, kb, vb, O, part0 + (size_t)sub * 16384, pls + (size_t)sub * 128,
              part1 + (size_t)sub * 16384, pls + (size_t)(256 + sub) * 128,
              cnt + sub, &lastflag,
              bt, 0, 15 - 2 * p, w, lane, quad, l15, smem, b, h, tid);
  } else {
    // tile-b suffix (17 iters, includes diagonal).
    attn_tile(qb, kb, vb, O, part1 + (size_t)sub * 16384, pls + (size_t)(256 + sub) * 128,
              part0 + (size_t)sub * 16384, pls + (size_t)sub * 128,
              cnt + sub, &lastflag,
              bt, 15 - 2 * p, 32 - 2 * p, w, lane, quad, l15, smem, b, h, tid);
  }
}

// ---------------------------------------------------------------------------
extern "C" void kernel_launch(void* const* d_in, const int* in_sizes, int n_in,
                              void* d_out, int out_size, void* d_ws, size_t ws_size,
                              hipStream_t stream) {
  const float* x = (const float*)d_in[0];   // [4,2048,1024] fp32
  const float* wq = (const float*)d_in[1];  // [8,1024,128] fp32
  const float* wk = (const float*)d_in[2];
  const float* wv = (const float*)d_in[3];
  const float* wo = (const float*)d_in[4];  // [8,128,1024] fp32
  float* out = (float*)d_out;               // [4,2048,1024] fp32 (32MB)

  char* ws = (char*)d_ws;
  const size_t SZ = 16777216;  // 16 MB per 8M-elem bf16 buffer
  u16* x_bf = (u16*)(ws);                   // [8192][1024] bf16; dead during flash
  u16* q_ws = (u16*)(ws + SZ);              // [bh][t][d]
  u16* k_ws = (u16*)(ws + 2 * SZ);          // [bh][t][d]
  u16* v_ws = (u16*)(ws + 3 * SZ);          // [bh][d][t'] (perm32 columns)
  u16* o_ws = (u16*)(ws + 4 * SZ);          // [b][t][h][d]
  u16* wT = (u16*)(ws + 5 * SZ);            // [3*1024][1024] bf16
  u16* woT = (u16*)(ws + 5 * SZ + 6291456); // [1024][1024] bf16
  float2* tab = (float2*)(ws + 5 * SZ + 6291456 + 2097152);  // [2048*64]
  int* cnt = (int*)(ws + 5 * SZ + 6291456 + 2097152 + 1048576);  // 256 ints
  // Partial buffers in DEAD scratch:
  //   part0: x_bf region (16MB, dead after gemm<0> reads it)
  //   part1 + pls: d_out (32MB; only written by the final gemm<1>)
  float* part0 = (float*)x_bf;              // 256 x 64KB = 16MB
  float* part1 = (float*)out;               // 16MB at d_out[0]
  float* pls = (float*)((char*)out + 16777216);  // 512*128*4 = 256KB

  prep_all<<<12800, 256, 0, stream>>>(x, wq, wk, wv, wo, x_bf, wT, woT, tab, cnt);
  gemm_bt<0><<<dim3(64, 24), 256, 0, stream>>>(x_bf, wT, q_ws, k_ws, v_ws, tab);
  flash_attn<<<512, 256, 0, stream>>>(q_ws, k_ws, v_ws, o_ws, part0, part1, pls, cnt);
  gemm_bt<1><<<dim3(64, 8), 256, 0, stream>>>(o_ws, woT, out, nullptr, nullptr, nullptr);
}

// Round 10
// 246.268 us; speedup vs baseline: 1.1956x; 1.1956x over previous
//
#include <hip/hip_runtime.h>
#include <math.h>

// Problem: MultiheadSelfAttention_41369124995143 on gfx950
// B=4, T=2048, M=1024, H=8, D=128.
// I/O is fp32 (per reference); internal compute bf16 MFMA with fp32 accum.

typedef unsigned short u16;
typedef __attribute__((ext_vector_type(8))) short short8;   // 8 bf16 = 4 VGPR (MFMA A/B frag)
typedef __attribute__((ext_vector_type(4))) float floatx4;  // MFMA C/D frag

#define MFMA_B16(a, b, c) __builtin_amdgcn_mfma_f32_16x16x32_bf16((a), (b), (c), 0, 0, 0)

__device__ __forceinline__ void async_cp16(const void* g, void* l) {
  // 16B global -> LDS DMA. LDS dest = wave-uniform base + lane*16.
  __builtin_amdgcn_global_load_lds(
      (const __attribute__((address_space(1))) unsigned int*)g,
      (__attribute__((address_space(3))) unsigned int*)l, 16, 0, 0);
}

__device__ __forceinline__ u16 f2bf(float f) {  // RNE float->bf16
  unsigned u = __float_as_uint(f);
  u += 0x7FFFu + ((u >> 16) & 1u);
  return (u16)(u >> 16);
}

__device__ __forceinline__ unsigned cvt_pk_bf16(float lo, float hi) {
  // v_cvt_pk_bf16_f32: dst.lo16 = bf16(lo), dst.hi16 = bf16(hi), RNE.
  unsigned r;
  asm("v_cvt_pk_bf16_f32 %0, %1, %2" : "=v"(r) : "v"(lo), "v"(hi));
  return r;
}

// XOR swizzle: 16B chunk c of logical row stored at physical chunk (c ^ (row&7)).
__device__ __forceinline__ int swz8(int row, int chunk) { return ((chunk ^ (row & 7)) << 3); }

// ---------------------------------------------------------------------------
// prep_all: ALL prep work in ONE kernel.
//   bid [0, 8192):      x fp32 -> bf16           (1024 elems/block)
//   bid [8192, 11264):  wq/wk/wv transpose -> wT (32x32 tiles)
//   bid [11264, 12288): wo transpose -> woT
//   bid [12288, 12800): rope table (256 entries/block)
// ---------------------------------------------------------------------------
__global__ void prep_all(const float* __restrict__ x, const float* __restrict__ wq,
                         const float* __restrict__ wk, const float* __restrict__ wv,
                         const float* __restrict__ wo, u16* __restrict__ xb,
                         u16* __restrict__ wT, u16* __restrict__ woT,
                         float2* __restrict__ tab) {
  __shared__ float tile[32][33];
  const int bid = blockIdx.x;
  const int tid = threadIdx.x;

  if (bid < 8192) {
    int idx = (bid * 256 + tid) * 4;
    float4 v = *(const float4*)(x + idx);
    ushort4 o = make_ushort4(f2bf(v.x), f2bf(v.y), f2bf(v.z), f2bf(v.w));
    *(ushort4*)(xb + idx) = o;
  } else if (bid < 11264) {
    int id2 = bid - 8192;
    int z = id2 >> 10;            // 0..2 (q,k,v)
    int rem = id2 & 1023;
    int by = rem >> 5, bx = rem & 31;
    const float* src = (z == 0) ? wq : (z == 1) ? wk : wv;
    u16* dst = wT + (size_t)z * 1024 * 1024;
    int h = by >> 2, dt = by & 3;
    int m0 = bx * 32, d0 = dt * 32;
    int tx = tid & 31, ty = tid >> 5;
#pragma unroll
    for (int i = 0; i < 4; i++) {
      int r = ty + i * 8;
      tile[r][tx] = src[((size_t)h * 1024 + m0 + r) * 128 + d0 + tx];
    }
    __syncthreads();
#pragma unroll
    for (int i = 0; i < 4; i++) {
      int r = ty + i * 8;
      dst[((size_t)h * 128 + d0 + r) * 1024 + m0 + tx] = f2bf(tile[tx][r]);
    }
  } else if (bid < 12288) {
    int id2 = bid - 11264;
    int by = id2 >> 5, bx = id2 & 31;
    int r0 = by * 32, c0 = bx * 32;
    int tx = tid & 31, ty = tid >> 5;
#pragma unroll
    for (int i = 0; i < 4; i++) {
      int r = ty + i * 8;
      tile[r][tx] = wo[(size_t)(r0 + r) * 1024 + c0 + tx];
    }
    __syncthreads();
#pragma unroll
    for (int i = 0; i < 4; i++) {
      int r = ty + i * 8;
      woT[(size_t)(c0 + r) * 1024 + r0 + tx] = f2bf(tile[tx][r]);
    }
  } else {
    // rope table: tab[t*64+d] = SQ * {cos,sin}(t * 10000^(-d/64)), fp32.
    // SQ = sqrt((1/128)*log2(e)): Q,K pre-scaled so softmax is plain exp2.
    int idx = (bid - 12288) * 256 + tid;  // 2048*64 entries
    int t = idx >> 6, d = idx & 63;
    const float c1 = -0.20762050593046015f;  // -log2(10000)/64
    const float SQ = 0.10616522f;            // sqrt((1/128)*log2(e))
    float freq = exp2f((float)d * c1);
    float rad = (float)t * freq;
    float s, c;
    sincosf(rad, &s, &c);
    tab[idx] = make_float2(c * SQ, s * SQ);
  }
}

// ---------------------------------------------------------------------------
// GEMM: C[128x128] = A[128xK] * Bt[128xK]^T, K=1024, BK=64, 4 waves,
// wave w owns rows [w*32, w*32+32) x ALL 128 cols (RoPE pairs in-lane).
// MODE 0: QKV projection (by: 0-7 Q, 8-15 K, 16-23 V); A,Bt bf16.
// MODE 1: output projection; fp32 store to out0.
// 128x128 tile kept deliberately: guide m105 measured 128x256 SLOWER (823
// vs 912 TF) at this 2-barrier structure; tile growth pays only with the
// 8-phase schedule.
// ---------------------------------------------------------------------------
template <int MODE>
__launch_bounds__(256, 3)
__global__ void gemm_bt(const u16* __restrict__ A, const u16* __restrict__ Bt,
                        void* __restrict__ out0, u16* __restrict__ out_k,
                        u16* __restrict__ out_v, const float2* __restrict__ ropetab) {
  __shared__ u16 smem[16384];  // As[128*64] | Bs[128*64]; reused as E[128*128] in V epilogue
  u16* As = smem;
  u16* Bs = smem + 8192;
  const int tid = threadIdx.x;
  const int w = tid >> 6, lane = tid & 63, quad = lane >> 4, l15 = lane & 15;
  const int row0 = blockIdx.x * 128;
  const int by = blockIdx.y;
  const int n0 = by * 128;

  floatx4 acc[2][8] = {};

  for (int kt = 0; kt < 16; ++kt) {
    __syncthreads();
#pragma unroll
    for (int i = 0; i < 4; i++) {
      int cidx = (w * 4 + i) * 64 + lane;  // 16B chunk id in 128x64 tile
      int r = cidx >> 3, c = cidx & 7, cg = c ^ (r & 7);
      async_cp16(A + (size_t)(row0 + r) * 1024 + kt * 64 + cg * 8, As + (w * 4 + i) * 512);
      async_cp16(Bt + (size_t)(n0 + r) * 1024 + kt * 64 + cg * 8, Bs + (w * 4 + i) * 512);
    }
    __syncthreads();
#pragma unroll
    for (int ks = 0; ks < 2; ks++) {
      short8 af[2];
#pragma unroll
      for (int mi = 0; mi < 2; mi++) {
        int r = w * 32 + mi * 16 + l15;
        af[mi] = *(const short8*)(As + r * 64 + swz8(r, ks * 4 + quad));
      }
#pragma unroll
      for (int ni = 0; ni < 8; ni++) {
        int n = ni * 16 + l15;
        short8 bf = *(const short8*)(Bs + n * 64 + swz8(n, ks * 4 + quad));
        acc[0][ni] = MFMA_B16(af[0], bf, acc[0][ni]);
        acc[1][ni] = MFMA_B16(af[1], bf, acc[1][ni]);
      }
    }
  }
  __syncthreads();

  if (MODE == 0) {
    int sel = by >> 3, h = by & 7;
    if (sel < 2) {
      // Q or K: in-register RoPE (cols d and d+64 share lane & reg). out [b][h][t][d] bf16.
      u16* dst = sel ? out_k : (u16*)out0;
#pragma unroll
      for (int mi = 0; mi < 2; mi++) {
#pragma unroll
        for (int reg = 0; reg < 4; reg++) {
          int row = row0 + w * 32 + mi * 16 + quad * 4 + reg;  // b*T + t
          int b = row >> 11, t = row & 2047;
          u16* drow = dst + ((size_t)(b * 8 + h) * 2048 + t) * 128;
#pragma unroll
          for (int ni = 0; ni < 4; ni++) {
            int d = ni * 16 + l15;  // 0..63
            float2 cs = ropetab[t * 64 + d];
            float e = acc[mi][ni][reg], o = acc[mi][ni + 4][reg];
            drow[d] = f2bf(e * cs.x - o * cs.y);
            drow[d + 64] = f2bf(e * cs.y + o * cs.x);
          }
        }
      }
    } else {
      // V: LDS transpose, store [b][h][d][t'] bf16 with t' = perm32'd t so
      // flash's PV B-operand k-slots match the in-register P layout:
      //   perm32(j) = ((j>>2)&3)*8 + (j&3) + ((j&16)>>2)
#pragma unroll
      for (int mi = 0; mi < 2; mi++) {
#pragma unroll
        for (int reg = 0; reg < 4; reg++) {
          int r = w * 32 + mi * 16 + quad * 4 + reg;
#pragma unroll
          for (int ni = 0; ni < 8; ni++) {
            int col = ni * 16 + l15;
            smem[r * 128 + swz8(r, col >> 3) + (col & 7)] = f2bf(acc[mi][ni][reg]);
          }
        }
      }
      __syncthreads();
      int tl = tid & 127, dg = tid >> 7;
      int row = row0 + tl;
      int b = row >> 11, t = row & 2047;
      int tp = (t & ~31) | ((((t >> 2) & 3) << 3) | (t & 3) | ((t & 16) >> 2));
      u16* vdst = out_v + (size_t)(b * 8 + h) * 128 * 2048;
#pragma unroll
      for (int dd = 0; dd < 64; dd++) {
        int d = dg * 64 + dd;
        u16 val = smem[tl * 128 + swz8(tl, d >> 3) + (d & 7)];
        vdst[(size_t)d * 2048 + tp] = val;  // consecutive tid -> coalesced
      }
    }
  } else {
    // MODE 1: fp32 store to out [8192][1024]
    float* outf = (float*)out0;
#pragma unroll
    for (int mi = 0; mi < 2; mi++) {
#pragma unroll
      for (int reg = 0; reg < 4; reg++) {
        int row = row0 + w * 32 + mi * 16 + quad * 4 + reg;
#pragma unroll
        for (int ni = 0; ni < 8; ni++) {
          outf[(size_t)row * 1024 + n0 + ni * 16 + l15] = acc[mi][ni][reg];
        }
      }
    }
  }
}

// ---------------------------------------------------------------------------
// Flash attention v8r: round-8 verified structure (237.0us total, flash
// 64.2us) + Q-frag hoist. Round-9's in-kernel merge REVERTED: its
// __threadfence() (device scope) must bridge non-coherent per-XCD L2s ->
// L2 writeback/invalidate inside the hot loop destroyed co-resident
// blocks' cached K/V (flash 64->120us, MfmaUtil 23->12). The separate
// combine kernel's launch boundary IS the cheap device-wide fence.
//   Balanced j-split (round-7 verified: 17 iters/block, occ 17.7%).
//   Pair (a=p, b=15-p), p=0..7:
//     W0 (id<256):  all of tile a (2p+2) -> direct O; tile-b [0,15-2p)
//     W1 (id>=256): tile-b [15-2p, 32-2p)   (contains b's diagonal)
//   FIXED-MAX softmax makes j-split ADDITIVE: fp32 partials just add;
//   combine kernel sums, normalizes, writes O. Exact.
//   Row-sum via ones-column MFMA. P never touches LDS (swapped QK^T +
//   perm32'd V). Q,K bf16 [bh][t][d]; V bf16 [bh][d][t']; O -> [b][t][h][d].
// ---------------------------------------------------------------------------
__device__ __forceinline__ void stage_kv(const u16* kb, const u16* vb, int jt,
                                         u16* Kd, u16* Vd, int w, int lane) {
#pragma unroll
  for (int i = 0; i < 4; i++) {
    int cidx = (w * 4 + i) * 64 + lane;  // 16B chunk id, 0..1023
    int rK = cidx >> 4, cK = cidx & 15, gK = cK ^ (rK & 7);
    async_cp16(kb + (size_t)(jt * 64 + rK) * 128 + gK * 8, Kd + (w * 4 + i) * 512);
    int rV = cidx >> 3, cV = cidx & 7, gV = cV ^ (rV & 7);
    async_cp16(vb + (size_t)rV * 2048 + jt * 64 + gV * 8, Vd + (w * 4 + i) * 512);
  }
}

__device__ __forceinline__ void attn_tile(
    const u16* __restrict__ qb, const u16* __restrict__ kb, const u16* __restrict__ vb,
    u16* __restrict__ O, float* __restrict__ partp, float* __restrict__ plp,
    int qt, int jb, int je, int w, int lane, int quad, int l15,
    u16* smem, int b, int h) {
  const int iw = qt * 128 + w * 32;  // wave's first global q-row

  // Q fragments: global reads with no smem dependency -> issue BEFORE the
  // entry barrier so their latency overlaps the barrier wait.
  short8 qf[2][4];
#pragma unroll
  for (int mi = 0; mi < 2; mi++) {
    int qrow = iw + mi * 16 + l15;
#pragma unroll
    for (int ks = 0; ks < 4; ks++)
      qf[mi][ks] = *(const short8*)(qb + (size_t)qrow * 128 + ks * 32 + quad * 8);
  }

  __syncthreads();  // prior phase's readers of smem are done

  short8 onesf;  // bf16 1.0 in all 8 slots: B-operand for row-sum MFMA
#pragma unroll
  for (int i = 0; i < 8; i++) onesf[i] = (short)0x3F80;

  floatx4 accO[2][8] = {};
  floatx4 accLs[2] = {};  // accLs[mi][r] = sum_j P[row(quad,r)][j], all l15 equal

  stage_kv(kb, vb, jb, smem, smem + 16384, w, lane);

  int cur = 0;
  for (int jt = jb; jt < je; ++jt) {
    __syncthreads();  // tile jt ready; other-buffer readers done
    if (jt + 1 < je)
      stage_kv(kb, vb, jt + 1, smem + (cur ^ 1) * 8192, smem + 16384 + (cur ^ 1) * 8192, w, lane);

    const u16* Ks = smem + cur * 8192;
    const u16* Vs = smem + 16384 + cur * 8192;
    const int j0 = jt * 64;

    if (j0 <= iw + 31) {  // else: whole KV tile above this wave's diagonal
      const bool partial = (j0 + 63 > iw);

      // S^T = K Q^T: sa[jj][mi], lane -> (i = l15 of strip mi, j = jj*16+quad*4+r)
      floatx4 sa[4][2] = {};
      __builtin_amdgcn_s_setprio(1);
#pragma unroll
      for (int jj = 0; jj < 4; jj++) {
        const bool ok1 = (j0 + jj * 16 <= iw + 31);
        if (!ok1) continue;
        const bool ok0 = (j0 + jj * 16 <= iw + 15);
#pragma unroll
        for (int ks = 0; ks < 4; ks++) {
          int j = jj * 16 + l15;
          short8 kf = *(const short8*)(Ks + j * 128 + swz8(j, ks * 4 + quad));
          if (ok0) sa[jj][0] = MFMA_B16(kf, qf[0][ks], sa[jj][0]);
          sa[jj][1] = MFMA_B16(kf, qf[1][ks], sa[jj][1]);
        }
      }
      __builtin_amdgcn_s_setprio(0);

      // p = exp2(s) with causal mask; pack to bf16 IN REGISTERS.
      unsigned pk_[2][2][4];
#pragma unroll
      for (int mi = 0; mi < 2; mi++) {
        const int ig = iw + mi * 16 + l15;
#pragma unroll
        for (int jj = 0; jj < 4; jj++) {
          float pv[4];
#pragma unroll
          for (int r = 0; r < 4; r++) {
            float s = sa[jj][mi][r];
            if (partial) {
              int jg = j0 + jj * 16 + quad * 4 + r;
              if (jg > ig) s = -1e30f;  // exp2 -> 0
            }
            pv[r] = exp2f(s);
          }
          pk_[mi][jj >> 1][(jj & 1) * 2 + 0] = cvt_pk_bf16(pv[0], pv[1]);
          pk_[mi][jj >> 1][(jj & 1) * 2 + 1] = cvt_pk_bf16(pv[2], pv[3]);
        }
      }

      // O += P*V; rowsum += P*ones (matrix pipe). V columns pre-permuted so
      // B k-slots match P's in-register layout.
      __builtin_amdgcn_s_setprio(1);
#pragma unroll
      for (int k2 = 0; k2 < 2; k2++) {
        if (k2 == 1 && j0 + 32 > iw + 31) continue;  // upper half fully masked
        union {
          unsigned u[4];
          short8 s8;
        } pa[2];
#pragma unroll
        for (int mi = 0; mi < 2; mi++) {
#pragma unroll
          for (int dw = 0; dw < 4; dw++) pa[mi].u[dw] = pk_[mi][k2][dw];
        }
        accLs[0] = MFMA_B16(pa[0].s8, onesf, accLs[0]);
        accLs[1] = MFMA_B16(pa[1].s8, onesf, accLs[1]);
#pragma unroll
        for (int nt = 0; nt < 8; nt++) {
          int dr = nt * 16 + l15;
          short8 vf = *(const short8*)(Vs + dr * 64 + swz8(dr, k2 * 4 + quad));
          accO[0][nt] = MFMA_B16(pa[0].s8, vf, accO[0][nt]);
          accO[1][nt] = MFMA_B16(pa[1].s8, vf, accO[1][nt]);
        }
      }
      __builtin_amdgcn_s_setprio(0);
    }
    cur ^= 1;
  }

  if (partp == nullptr) {
    // Tile complete: normalize + store O as [b][t][h][d] bf16.
#pragma unroll
    for (int mi = 0; mi < 2; mi++) {
#pragma unroll
      for (int r = 0; r < 4; r++) {
        float inv = 1.0f / fmaxf(accLs[mi][r], 1e-30f);
        int t = iw + mi * 16 + quad * 4 + r;
#pragma unroll
        for (int nt = 0; nt < 8; nt++) {
          O[(((size_t)b * 2048 + t) * 8 + h) * 128 + nt * 16 + l15] =
              f2bf(accO[mi][nt][r] * inv);
        }
      }
    }
  } else {
    // Partial: fp32 numerators [128][128] + row-sums [128].
#pragma unroll
    for (int mi = 0; mi < 2; mi++) {
#pragma unroll
      for (int r = 0; r < 4; r++) {
        int lrow = w * 32 + mi * 16 + quad * 4 + r;
#pragma unroll
        for (int nt = 0; nt < 8; nt++) {
          partp[lrow * 128 + nt * 16 + l15] = accO[mi][nt][r];
        }
        if (l15 == 0) plp[lrow] = accLs[mi][r];
      }
    }
  }
}

__launch_bounds__(256, 2)
__global__ void flash_attn(const u16* __restrict__ Q, const u16* __restrict__ Kw,
                           const u16* __restrict__ Vw, u16* __restrict__ O,
                           float* __restrict__ part0, float* __restrict__ part1,
                           float* __restrict__ pls) {
  // 64KB dbuf: K0 [0,8192), K1 [8192,16384), V0 [16384,24576), V1 [24576,32768)
  __shared__ u16 smem[32768];

  const int tid = threadIdx.x;
  const int w = tid >> 6, lane = tid & 63, quad = lane >> 4, l15 = lane & 15;

  const int id = (int)blockIdx.x;  // 0..511
  const int half = id >> 8;        // 0 = W0, 1 = W1
  const int sub = id & 255;        // job id: p*32 + bh
  const int bh = sub & 31, p = sub >> 5;

  const u16* qb = Q + (size_t)bh * 2048 * 128;
  const u16* kb = Kw + (size_t)bh * 2048 * 128;
  const u16* vb = Vw + (size_t)bh * 128 * 2048;
  const int b = bh >> 3, h = bh & 7;
  const int bt = 15 - p;  // partner tile

  if (half == 0) {
    // tile a complete (2p+2 iters) -> direct O; then tile-b prefix (15-2p).
    attn_tile(qb, kb, vb, O, nullptr, nullptr, p, 0, 2 * p + 2,
              w, lane, quad, l15, smem, b, h);
    attn_tile(qb, kb, vb, O, part0 + (size_t)sub * 16384, pls + (size_t)sub * 128,
              bt, 0, 15 - 2 * p, w, lane, quad, l15, smem, b, h);
  } else {
    // tile-b suffix (17 iters, includes diagonal).
    attn_tile(qb, kb, vb, O, part1 + (size_t)sub * 16384, pls + (size_t)(256 + sub) * 128,
              bt, 15 - 2 * p, 32 - 2 * p, w, lane, quad, l15, smem, b, h);
  }
}

// Combine: O[tile b] = (part0 + part1) / (pl0 + pl1). 256 jobs (p*32+bh).
__global__ void combine(const float* __restrict__ part0, const float* __restrict__ part1,
                        const float* __restrict__ pls, u16* __restrict__ O) {
  __shared__ float ls[128];
  const int job = blockIdx.x;
  const int bh = job & 31, p = job >> 5;
  const int bt = 15 - p;
  const int bb = bh >> 3, h = bh & 7;
  const float* P0 = part0 + (size_t)job * 16384;
  const float* P1 = part1 + (size_t)job * 16384;
  if (threadIdx.x < 128) {
    float s = pls[(size_t)job * 128 + threadIdx.x] + pls[(size_t)(256 + job) * 128 + threadIdx.x];
    ls[threadIdx.x] = 1.0f / fmaxf(s, 1e-30f);
  }
  __syncthreads();
  for (int e = threadIdx.x; e < 16384; e += 256) {
    int row = e >> 7, col = e & 127;
    float v = (P0[e] + P1[e]) * ls[row];
    int t = bt * 128 + row;
    O[(((size_t)bb * 2048 + t) * 8 + h) * 128 + col] = f2bf(v);
  }
}

// ---------------------------------------------------------------------------
extern "C" void kernel_launch(void* const* d_in, const int* in_sizes, int n_in,
                              void* d_out, int out_size, void* d_ws, size_t ws_size,
                              hipStream_t stream) {
  const float* x = (const float*)d_in[0];   // [4,2048,1024] fp32
  const float* wq = (const float*)d_in[1];  // [8,1024,128] fp32
  const float* wk = (const float*)d_in[2];
  const float* wv = (const float*)d_in[3];
  const float* wo = (const float*)d_in[4];  // [8,128,1024] fp32
  float* out = (float*)d_out;               // [4,2048,1024] fp32 (32MB)

  char* ws = (char*)d_ws;
  const size_t SZ = 16777216;  // 16 MB per 8M-elem bf16 buffer
  u16* x_bf = (u16*)(ws);                   // [8192][1024] bf16; dead during flash
  u16* q_ws = (u16*)(ws + SZ);              // [bh][t][d]
  u16* k_ws = (u16*)(ws + 2 * SZ);          // [bh][t][d]
  u16* v_ws = (u16*)(ws + 3 * SZ);          // [bh][d][t'] (perm32 columns)
  u16* o_ws = (u16*)(ws + 4 * SZ);          // [b][t][h][d]
  u16* wT = (u16*)(ws + 5 * SZ);            // [3*1024][1024] bf16
  u16* woT = (u16*)(ws + 5 * SZ + 6291456); // [1024][1024] bf16
  float2* tab = (float2*)(ws + 5 * SZ + 6291456 + 2097152);  // [2048*64]
  // Partial buffers in DEAD scratch (round-3..5-proven footprint):
  //   part0: x_bf region (16MB, dead after gemm<0> reads it)
  //   part1 + pls: d_out (32MB; only written by the final gemm<1>)
  float* part0 = (float*)x_bf;              // 256 x 64KB = 16MB
  float* part1 = (float*)out;               // 16MB at d_out[0]
  float* pls = (float*)((char*)out + 16777216);  // 512*128*4 = 256KB

  prep_all<<<12800, 256, 0, stream>>>(x, wq, wk, wv, wo, x_bf, wT, woT, tab);
  gemm_bt<0><<<dim3(64, 24), 256, 0, stream>>>(x_bf, wT, q_ws, k_ws, v_ws, tab);
  flash_attn<<<512, 256, 0, stream>>>(q_ws, k_ws, v_ws, o_ws, part0, part1, pls);
  combine<<<256, 256, 0, stream>>>(part0, part1, pls, o_ws);
  gemm_bt<1><<<dim3(64, 8), 256, 0, stream>>>(o_ws, woT, out, nullptr, nullptr, nullptr);
}

// Round 11
// 236.068 us; speedup vs baseline: 1.2472x; 1.0432x over previous
//
#include <hip/hip_runtime.h>
#include <math.h>

// Problem: MultiheadSelfAttention_41369124995143 on gfx950
// B=4, T=2048, M=1024, H=8, D=128.
// I/O is fp32 (per reference); internal compute bf16 MFMA with fp32 accum.

typedef unsigned short u16;
typedef __attribute__((ext_vector_type(8))) short short8;   // 8 bf16 = 4 VGPR (MFMA A/B frag)
typedef __attribute__((ext_vector_type(4))) float floatx4;  // MFMA C/D frag

#define MFMA_B16(a, b, c) __builtin_amdgcn_mfma_f32_16x16x32_bf16((a), (b), (c), 0, 0, 0)

__device__ __forceinline__ void async_cp16(const void* g, void* l) {
  // 16B global -> LDS DMA. LDS dest = wave-uniform base + lane*16.
  __builtin_amdgcn_global_load_lds(
      (const __attribute__((address_space(1))) unsigned int*)g,
      (__attribute__((address_space(3))) unsigned int*)l, 16, 0, 0);
}

__device__ __forceinline__ u16 f2bf(float f) {  // RNE float->bf16
  unsigned u = __float_as_uint(f);
  u += 0x7FFFu + ((u >> 16) & 1u);
  return (u16)(u >> 16);
}

__device__ __forceinline__ unsigned cvt_pk_bf16(float lo, float hi) {
  // v_cvt_pk_bf16_f32: dst.lo16 = bf16(lo), dst.hi16 = bf16(hi), RNE.
  unsigned r;
  asm("v_cvt_pk_bf16_f32 %0, %1, %2" : "=v"(r) : "v"(lo), "v"(hi));
  return r;
}

// XOR swizzle: 16B chunk c of logical row stored at physical chunk (c ^ (row&7)).
__device__ __forceinline__ int swz8(int row, int chunk) { return ((chunk ^ (row & 7)) << 3); }

// ---------------------------------------------------------------------------
// prep_all: ALL prep work in ONE kernel.
//   bid [0, 8192):      x fp32 -> bf16           (1024 elems/block)
//   bid [8192, 11264):  wq/wk/wv transpose -> wT (32x32 tiles)
//   bid [11264, 12288): wo transpose -> woT
//   bid [12288, 12800): rope table (256 entries/block)
// ---------------------------------------------------------------------------
__global__ void prep_all(const float* __restrict__ x, const float* __restrict__ wq,
                         const float* __restrict__ wk, const float* __restrict__ wv,
                         const float* __restrict__ wo, u16* __restrict__ xb,
                         u16* __restrict__ wT, u16* __restrict__ woT,
                         float2* __restrict__ tab) {
  __shared__ float tile[32][33];
  const int bid = blockIdx.x;
  const int tid = threadIdx.x;

  if (bid < 8192) {
    int idx = (bid * 256 + tid) * 4;
    float4 v = *(const float4*)(x + idx);
    ushort4 o = make_ushort4(f2bf(v.x), f2bf(v.y), f2bf(v.z), f2bf(v.w));
    *(ushort4*)(xb + idx) = o;
  } else if (bid < 11264) {
    int id2 = bid - 8192;
    int z = id2 >> 10;            // 0..2 (q,k,v)
    int rem = id2 & 1023;
    int by = rem >> 5, bx = rem & 31;
    const float* src = (z == 0) ? wq : (z == 1) ? wk : wv;
    u16* dst = wT + (size_t)z * 1024 * 1024;
    int h = by >> 2, dt = by & 3;
    int m0 = bx * 32, d0 = dt * 32;
    int tx = tid & 31, ty = tid >> 5;
#pragma unroll
    for (int i = 0; i < 4; i++) {
      int r = ty + i * 8;
      tile[r][tx] = src[((size_t)h * 1024 + m0 + r) * 128 + d0 + tx];
    }
    __syncthreads();
#pragma unroll
    for (int i = 0; i < 4; i++) {
      int r = ty + i * 8;
      dst[((size_t)h * 128 + d0 + r) * 1024 + m0 + tx] = f2bf(tile[tx][r]);
    }
  } else if (bid < 12288) {
    int id2 = bid - 11264;
    int by = id2 >> 5, bx = id2 & 31;
    int r0 = by * 32, c0 = bx * 32;
    int tx = tid & 31, ty = tid >> 5;
#pragma unroll
    for (int i = 0; i < 4; i++) {
      int r = ty + i * 8;
      tile[r][tx] = wo[(size_t)(r0 + r) * 1024 + c0 + tx];
    }
    __syncthreads();
#pragma unroll
    for (int i = 0; i < 4; i++) {
      int r = ty + i * 8;
      woT[(size_t)(c0 + r) * 1024 + r0 + tx] = f2bf(tile[tx][r]);
    }
  } else {
    // rope table: tab[t*64+d] = SQ * {cos,sin}(t * 10000^(-d/64)), fp32.
    // SQ = sqrt((1/128)*log2(e)): Q,K pre-scaled so softmax is plain exp2.
    int idx = (bid - 12288) * 256 + tid;  // 2048*64 entries
    int t = idx >> 6, d = idx & 63;
    const float c1 = -0.20762050593046015f;  // -log2(10000)/64
    const float SQ = 0.10616522f;            // sqrt((1/128)*log2(e))
    float freq = exp2f((float)d * c1);
    float rad = (float)t * freq;
    float s, c;
    sincosf(rad, &s, &c);
    tab[idx] = make_float2(c * SQ, s * SQ);
  }
}

// ---------------------------------------------------------------------------
// GEMM: C[128x128] = A[128xK] * Bt[128xK]^T, K=1024, BK=64, 4 waves,
// wave w owns rows [w*32, w*32+32) x ALL 128 cols (RoPE pairs in-lane).
// MODE 0: QKV projection (by: 0-7 Q, 8-15 K, 16-23 V); A,Bt bf16.
// MODE 1: output projection; fp32 store to out0.
// 128x128 tile kept deliberately: guide m105 measured 128x256 SLOWER (823
// vs 912 TF) at this 2-barrier structure; tile growth pays only with the
// 8-phase schedule.
// ---------------------------------------------------------------------------
template <int MODE>
__launch_bounds__(256, 3)
__global__ void gemm_bt(const u16* __restrict__ A, const u16* __restrict__ Bt,
                        void* __restrict__ out0, u16* __restrict__ out_k,
                        u16* __restrict__ out_v, const float2* __restrict__ ropetab) {
  __shared__ u16 smem[16384];  // As[128*64] | Bs[128*64]; reused as E[128*128] in V epilogue
  u16* As = smem;
  u16* Bs = smem + 8192;
  const int tid = threadIdx.x;
  const int w = tid >> 6, lane = tid & 63, quad = lane >> 4, l15 = lane & 15;
  const int row0 = blockIdx.x * 128;
  const int by = blockIdx.y;
  const int n0 = by * 128;

  floatx4 acc[2][8] = {};

  for (int kt = 0; kt < 16; ++kt) {
    __syncthreads();
#pragma unroll
    for (int i = 0; i < 4; i++) {
      int cidx = (w * 4 + i) * 64 + lane;  // 16B chunk id in 128x64 tile
      int r = cidx >> 3, c = cidx & 7, cg = c ^ (r & 7);
      async_cp16(A + (size_t)(row0 + r) * 1024 + kt * 64 + cg * 8, As + (w * 4 + i) * 512);
      async_cp16(Bt + (size_t)(n0 + r) * 1024 + kt * 64 + cg * 8, Bs + (w * 4 + i) * 512);
    }
    __syncthreads();
#pragma unroll
    for (int ks = 0; ks < 2; ks++) {
      short8 af[2];
#pragma unroll
      for (int mi = 0; mi < 2; mi++) {
        int r = w * 32 + mi * 16 + l15;
        af[mi] = *(const short8*)(As + r * 64 + swz8(r, ks * 4 + quad));
      }
#pragma unroll
      for (int ni = 0; ni < 8; ni++) {
        int n = ni * 16 + l15;
        short8 bf = *(const short8*)(Bs + n * 64 + swz8(n, ks * 4 + quad));
        acc[0][ni] = MFMA_B16(af[0], bf, acc[0][ni]);
        acc[1][ni] = MFMA_B16(af[1], bf, acc[1][ni]);
      }
    }
  }
  __syncthreads();

  if (MODE == 0) {
    int sel = by >> 3, h = by & 7;
    if (sel < 2) {
      // Q or K: in-register RoPE (cols d and d+64 share lane & reg). out [b][h][t][d] bf16.
      u16* dst = sel ? out_k : (u16*)out0;
#pragma unroll
      for (int mi = 0; mi < 2; mi++) {
#pragma unroll
        for (int reg = 0; reg < 4; reg++) {
          int row = row0 + w * 32 + mi * 16 + quad * 4 + reg;  // b*T + t
          int b = row >> 11, t = row & 2047;
          u16* drow = dst + ((size_t)(b * 8 + h) * 2048 + t) * 128;
#pragma unroll
          for (int ni = 0; ni < 4; ni++) {
            int d = ni * 16 + l15;  // 0..63
            float2 cs = ropetab[t * 64 + d];
            float e = acc[mi][ni][reg], o = acc[mi][ni + 4][reg];
            drow[d] = f2bf(e * cs.x - o * cs.y);
            drow[d + 64] = f2bf(e * cs.y + o * cs.x);
          }
        }
      }
    } else {
      // V: LDS transpose, store [b][h][d][t'] bf16 with t' = perm32'd t so
      // flash's PV B-operand k-slots match the in-register P layout:
      //   perm32(j) = ((j>>2)&3)*8 + (j&3) + ((j&16)>>2)
#pragma unroll
      for (int mi = 0; mi < 2; mi++) {
#pragma unroll
        for (int reg = 0; reg < 4; reg++) {
          int r = w * 32 + mi * 16 + quad * 4 + reg;
#pragma unroll
          for (int ni = 0; ni < 8; ni++) {
            int col = ni * 16 + l15;
            smem[r * 128 + swz8(r, col >> 3) + (col & 7)] = f2bf(acc[mi][ni][reg]);
          }
        }
      }
      __syncthreads();
      int tl = tid & 127, dg = tid >> 7;
      int row = row0 + tl;
      int b = row >> 11, t = row & 2047;
      int tp = (t & ~31) | ((((t >> 2) & 3) << 3) | (t & 3) | ((t & 16) >> 2));
      u16* vdst = out_v + (size_t)(b * 8 + h) * 128 * 2048;
#pragma unroll
      for (int dd = 0; dd < 64; dd++) {
        int d = dg * 64 + dd;
        u16 val = smem[tl * 128 + swz8(tl, d >> 3) + (d & 7)];
        vdst[(size_t)d * 2048 + tp] = val;  // consecutive tid -> coalesced
      }
    }
  } else {
    // MODE 1: fp32 store to out [8192][1024]
    float* outf = (float*)out0;
#pragma unroll
    for (int mi = 0; mi < 2; mi++) {
#pragma unroll
      for (int reg = 0; reg < 4; reg++) {
        int row = row0 + w * 32 + mi * 16 + quad * 4 + reg;
#pragma unroll
        for (int ni = 0; ni < 8; ni++) {
          outf[(size_t)row * 1024 + n0 + ni * 16 + l15] = acc[mi][ni][reg];
        }
      }
    }
  }
}

// ---------------------------------------------------------------------------
// Flash attention v10: round-10 structure with ALL s_setprio REMOVED.
//   Theory: S_SETPRIO has unmodeled side effects -> compiler cannot move
//   instructions across it. The setprio(1)/(0) pairs around the QK and PV
//   MFMA clusters fenced the softmax VALU block (32 v_exp + 16 cvt_pk per
//   lane-iter) into its own scheduling region, FORBIDDING the interleave of
//   exp2/cvt into MFMA dependency-stall slots. With lockstep 4-wave blocks
//   (no wave role diversity) setprio gives none of its T5 upside (m190
//   null case) while paying this scheduling penalty. No barriers separate
//   the phases inside an iter, so removing the fences lets the scheduler
//   mix QK-MFMA / softmax-VALU / PV-MFMA freely.
//   Everything else identical to round-10 (flash 61.7us, occ 17.8%,
//   MfmaUtil 23.7%): balanced j-split, 17 iters/block, fixed-max softmax,
//   additive fp32 partials + separate combine kernel, ones-column-MFMA
//   row-sum, P-in-registers via swapped QK^T + perm32'd V, Q-frag hoist.
//   Q,K bf16 [bh][t][d]; V bf16 [bh][d][t']; O bf16 -> [b][t][h][d].
// ---------------------------------------------------------------------------
__device__ __forceinline__ void stage_kv(const u16* kb, const u16* vb, int jt,
                                         u16* Kd, u16* Vd, int w, int lane) {
#pragma unroll
  for (int i = 0; i < 4; i++) {
    int cidx = (w * 4 + i) * 64 + lane;  // 16B chunk id, 0..1023
    int rK = cidx >> 4, cK = cidx & 15, gK = cK ^ (rK & 7);
    async_cp16(kb + (size_t)(jt * 64 + rK) * 128 + gK * 8, Kd + (w * 4 + i) * 512);
    int rV = cidx >> 3, cV = cidx & 7, gV = cV ^ (rV & 7);
    async_cp16(vb + (size_t)rV * 2048 + jt * 64 + gV * 8, Vd + (w * 4 + i) * 512);
  }
}

__device__ __forceinline__ void attn_tile(
    const u16* __restrict__ qb, const u16* __restrict__ kb, const u16* __restrict__ vb,
    u16* __restrict__ O, float* __restrict__ partp, float* __restrict__ plp,
    int qt, int jb, int je, int w, int lane, int quad, int l15,
    u16* smem, int b, int h) {
  const int iw = qt * 128 + w * 32;  // wave's first global q-row

  // Q fragments: global reads with no smem dependency -> issue BEFORE the
  // entry barrier so their latency overlaps the barrier wait.
  short8 qf[2][4];
#pragma unroll
  for (int mi = 0; mi < 2; mi++) {
    int qrow = iw + mi * 16 + l15;
#pragma unroll
    for (int ks = 0; ks < 4; ks++)
      qf[mi][ks] = *(const short8*)(qb + (size_t)qrow * 128 + ks * 32 + quad * 8);
  }

  __syncthreads();  // prior phase's readers of smem are done

  short8 onesf;  // bf16 1.0 in all 8 slots: B-operand for row-sum MFMA
#pragma unroll
  for (int i = 0; i < 8; i++) onesf[i] = (short)0x3F80;

  floatx4 accO[2][8] = {};
  floatx4 accLs[2] = {};  // accLs[mi][r] = sum_j P[row(quad,r)][j], all l15 equal

  stage_kv(kb, vb, jb, smem, smem + 16384, w, lane);

  int cur = 0;
  for (int jt = jb; jt < je; ++jt) {
    __syncthreads();  // tile jt ready; other-buffer readers done
    if (jt + 1 < je)
      stage_kv(kb, vb, jt + 1, smem + (cur ^ 1) * 8192, smem + 16384 + (cur ^ 1) * 8192, w, lane);

    const u16* Ks = smem + cur * 8192;
    const u16* Vs = smem + 16384 + cur * 8192;
    const int j0 = jt * 64;

    if (j0 <= iw + 31) {  // else: whole KV tile above this wave's diagonal
      const bool partial = (j0 + 63 > iw);

      // S^T = K Q^T: sa[jj][mi], lane -> (i = l15 of strip mi, j = jj*16+quad*4+r)
      floatx4 sa[4][2] = {};
#pragma unroll
      for (int jj = 0; jj < 4; jj++) {
        const bool ok1 = (j0 + jj * 16 <= iw + 31);
        if (!ok1) continue;
        const bool ok0 = (j0 + jj * 16 <= iw + 15);
#pragma unroll
        for (int ks = 0; ks < 4; ks++) {
          int j = jj * 16 + l15;
          short8 kf = *(const short8*)(Ks + j * 128 + swz8(j, ks * 4 + quad));
          if (ok0) sa[jj][0] = MFMA_B16(kf, qf[0][ks], sa[jj][0]);
          sa[jj][1] = MFMA_B16(kf, qf[1][ks], sa[jj][1]);
        }
      }

      // p = exp2(s) with causal mask; pack to bf16 IN REGISTERS.
      unsigned pk_[2][2][4];
#pragma unroll
      for (int mi = 0; mi < 2; mi++) {
        const int ig = iw + mi * 16 + l15;
#pragma unroll
        for (int jj = 0; jj < 4; jj++) {
          float pv[4];
#pragma unroll
          for (int r = 0; r < 4; r++) {
            float s = sa[jj][mi][r];
            if (partial) {
              int jg = j0 + jj * 16 + quad * 4 + r;
              if (jg > ig) s = -1e30f;  // exp2 -> 0
            }
            pv[r] = exp2f(s);
          }
          pk_[mi][jj >> 1][(jj & 1) * 2 + 0] = cvt_pk_bf16(pv[0], pv[1]);
          pk_[mi][jj >> 1][(jj & 1) * 2 + 1] = cvt_pk_bf16(pv[2], pv[3]);
        }
      }

      // O += P*V; rowsum += P*ones (matrix pipe). V columns pre-permuted so
      // B k-slots match P's in-register layout.
#pragma unroll
      for (int k2 = 0; k2 < 2; k2++) {
        if (k2 == 1 && j0 + 32 > iw + 31) continue;  // upper half fully masked
        union {
          unsigned u[4];
          short8 s8;
        } pa[2];
#pragma unroll
        for (int mi = 0; mi < 2; mi++) {
#pragma unroll
          for (int dw = 0; dw < 4; dw++) pa[mi].u[dw] = pk_[mi][k2][dw];
        }
        accLs[0] = MFMA_B16(pa[0].s8, onesf, accLs[0]);
        accLs[1] = MFMA_B16(pa[1].s8, onesf, accLs[1]);
#pragma unroll
        for (int nt = 0; nt < 8; nt++) {
          int dr = nt * 16 + l15;
          short8 vf = *(const short8*)(Vs + dr * 64 + swz8(dr, k2 * 4 + quad));
          accO[0][nt] = MFMA_B16(pa[0].s8, vf, accO[0][nt]);
          accO[1][nt] = MFMA_B16(pa[1].s8, vf, accO[1][nt]);
        }
      }
    }
    cur ^= 1;
  }

  if (partp == nullptr) {
    // Tile complete: normalize + store O as [b][t][h][d] bf16.
#pragma unroll
    for (int mi = 0; mi < 2; mi++) {
#pragma unroll
      for (int r = 0; r < 4; r++) {
        float inv = 1.0f / fmaxf(accLs[mi][r], 1e-30f);
        int t = iw + mi * 16 + quad * 4 + r;
#pragma unroll
        for (int nt = 0; nt < 8; nt++) {
          O[(((size_t)b * 2048 + t) * 8 + h) * 128 + nt * 16 + l15] =
              f2bf(accO[mi][nt][r] * inv);
        }
      }
    }
  } else {
    // Partial: fp32 numerators [128][128] + row-sums [128].
#pragma unroll
    for (int mi = 0; mi < 2; mi++) {
#pragma unroll
      for (int r = 0; r < 4; r++) {
        int lrow = w * 32 + mi * 16 + quad * 4 + r;
#pragma unroll
        for (int nt = 0; nt < 8; nt++) {
          partp[lrow * 128 + nt * 16 + l15] = accO[mi][nt][r];
        }
        if (l15 == 0) plp[lrow] = accLs[mi][r];
      }
    }
  }
}

__launch_bounds__(256, 2)
__global__ void flash_attn(const u16* __restrict__ Q, const u16* __restrict__ Kw,
                           const u16* __restrict__ Vw, u16* __restrict__ O,
                           float* __restrict__ part0, float* __restrict__ part1,
                           float* __restrict__ pls) {
  // 64KB dbuf: K0 [0,8192), K1 [8192,16384), V0 [16384,24576), V1 [24576,32768)
  __shared__ u16 smem[32768];

  const int tid = threadIdx.x;
  const int w = tid >> 6, lane = tid & 63, quad = lane >> 4, l15 = lane & 15;

  const int id = (int)blockIdx.x;  // 0..511
  const int half = id >> 8;        // 0 = W0, 1 = W1
  const int sub = id & 255;        // job id: p*32 + bh
  const int bh = sub & 31, p = sub >> 5;

  const u16* qb = Q + (size_t)bh * 2048 * 128;
  const u16* kb = Kw + (size_t)bh * 2048 * 128;
  const u16* vb = Vw + (size_t)bh * 128 * 2048;
  const int b = bh >> 3, h = bh & 7;
  const int bt = 15 - p;  // partner tile

  if (half == 0) {
    // tile a complete (2p+2 iters) -> direct O; then tile-b prefix (15-2p).
    attn_tile(qb, kb, vb, O, nullptr, nullptr, p, 0, 2 * p + 2,
              w, lane, quad, l15, smem, b, h);
    attn_tile(qb, kb, vb, O, part0 + (size_t)sub * 16384, pls + (size_t)sub * 128,
              bt, 0, 15 - 2 * p, w, lane, quad, l15, smem, b, h);
  } else {
    // tile-b suffix (17 iters, includes diagonal).
    attn_tile(qb, kb, vb, O, part1 + (size_t)sub * 16384, pls + (size_t)(256 + sub) * 128,
              bt, 15 - 2 * p, 32 - 2 * p, w, lane, quad, l15, smem, b, h);
  }
}

// Combine: O[tile b] = (part0 + part1) / (pl0 + pl1). 256 jobs (p*32+bh).
__global__ void combine(const float* __restrict__ part0, const float* __restrict__ part1,
                        const float* __restrict__ pls, u16* __restrict__ O) {
  __shared__ float ls[128];
  const int job = blockIdx.x;
  const int bh = job & 31, p = job >> 5;
  const int bt = 15 - p;
  const int bb = bh >> 3, h = bh & 7;
  const float* P0 = part0 + (size_t)job * 16384;
  const float* P1 = part1 + (size_t)job * 16384;
  if (threadIdx.x < 128) {
    float s = pls[(size_t)job * 128 + threadIdx.x] + pls[(size_t)(256 + job) * 128 + threadIdx.x];
    ls[threadIdx.x] = 1.0f / fmaxf(s, 1e-30f);
  }
  __syncthreads();
  for (int e = threadIdx.x; e < 16384; e += 256) {
    int row = e >> 7, col = e & 127;
    float v = (P0[e] + P1[e]) * ls[row];
    int t = bt * 128 + row;
    O[(((size_t)bb * 2048 + t) * 8 + h) * 128 + col] = f2bf(v);
  }
}

// ---------------------------------------------------------------------------
extern "C" void kernel_launch(void* const* d_in, const int* in_sizes, int n_in,
                              void* d_out, int out_size, void* d_ws, size_t ws_size,
                              hipStream_t stream) {
  const float* x = (const float*)d_in[0];   // [4,2048,1024] fp32
  const float* wq = (const float*)d_in[1];  // [8,1024,128] fp32
  const float* wk = (const float*)d_in[2];
  const float* wv = (const float*)d_in[3];
  const float* wo = (const float*)d_in[4];  // [8,128,1024] fp32
  float* out = (float*)d_out;               // [4,2048,1024] fp32 (32MB)

  char* ws = (char*)d_ws;
  const size_t SZ = 16777216;  // 16 MB per 8M-elem bf16 buffer
  u16* x_bf = (u16*)(ws);                   // [8192][1024] bf16; dead during flash
  u16* q_ws = (u16*)(ws + SZ);              // [bh][t][d]
  u16* k_ws = (u16*)(ws + 2 * SZ);          // [bh][t][d]
  u16* v_ws = (u16*)(ws + 3 * SZ);          // [bh][d][t'] (perm32 columns)
  u16* o_ws = (u16*)(ws + 4 * SZ);          // [b][t][h][d]
  u16* wT = (u16*)(ws + 5 * SZ);            // [3*1024][1024] bf16
  u16* woT = (u16*)(ws + 5 * SZ + 6291456); // [1024][1024] bf16
  float2* tab = (float2*)(ws + 5 * SZ + 6291456 + 2097152);  // [2048*64]
  // Partial buffers in DEAD scratch (round-3..5-proven footprint):
  //   part0: x_bf region (16MB, dead after gemm<0> reads it)
  //   part1 + pls: d_out (32MB; only written by the final gemm<1>)
  float* part0 = (float*)x_bf;              // 256 x 64KB = 16MB
  float* part1 = (float*)out;               // 16MB at d_out[0]
  float* pls = (float*)((char*)out + 16777216);  // 512*128*4 = 256KB

  prep_all<<<12800, 256, 0, stream>>>(x, wq, wk, wv, wo, x_bf, wT, woT, tab);
  gemm_bt<0><<<dim3(64, 24), 256, 0, stream>>>(x_bf, wT, q_ws, k_ws, v_ws, tab);
  flash_attn<<<512, 256, 0, stream>>>(q_ws, k_ws, v_ws, o_ws, part0, part1, pls);
  combine<<<256, 256, 0, stream>>>(part0, part1, pls, o_ws);
  gemm_bt<1><<<dim3(64, 8), 256, 0, stream>>>(o_ws, woT, out, nullptr, nullptr, nullptr);
}